// Round 3
// baseline (219.635 us; speedup 1.0000x reference)
//
#include <hip/hip_runtime.h>
#include <hip/hip_bf16.h>

typedef unsigned short ushort_t;
typedef unsigned int uint32;
typedef __attribute__((ext_vector_type(8))) short short8;
typedef __attribute__((ext_vector_type(4))) float f32x4;

// Problem constants: B=2, S=2048, D=1024, H=16, DK=64
#define NB 2
#define NS 2048
#define ND 1024
#define NH 16

__device__ __forceinline__ float bf2f(ushort_t u) {
  return __uint_as_float(((uint32)u) << 16);
}
__device__ __forceinline__ ushort_t f2bf(float x) {
  uint32 u = __float_as_uint(x);
  uint32 r = u + 0x7FFFu + ((u >> 16) & 1u);  // RNE
  return (ushort_t)(r >> 16);
}

__device__ __forceinline__ void gload16(const void* g, void* l) {
  __builtin_amdgcn_global_load_lds(
      (const __attribute__((address_space(1))) void*)g,
      (__attribute__((address_space(3))) void*)l, 16, 0, 0);
}

// ---------------------------------------------------------------------------
// fp32 -> bf16 convert: 7 segments (q,k,v: 2048 blocks each; 4 weights: 512
// blocks each). Each block converts 2048 elements (256 thr x 8).
// ---------------------------------------------------------------------------
__global__ __launch_bounds__(256) void convert_kernel(
    const float* q, const float* k, const float* v, const float* wq,
    const float* wk, const float* wv, const float* wo, ushort_t* Xq,
    ushort_t* Xk, ushort_t* Xv, ushort_t* Wq, ushort_t* Wk, ushort_t* Wv,
    ushort_t* Wo) {
  const int blk = blockIdx.x;
  const float* src;
  ushort_t* dst;
  int base;
  if (blk < 2048) { src = q; dst = Xq; base = blk; }
  else if (blk < 4096) { src = k; dst = Xk; base = blk - 2048; }
  else if (blk < 6144) { src = v; dst = Xv; base = blk - 4096; }
  else if (blk < 6656) { src = wq; dst = Wq; base = blk - 6144; }
  else if (blk < 7168) { src = wk; dst = Wk; base = blk - 6656; }
  else if (blk < 7680) { src = wv; dst = Wv; base = blk - 7168; }
  else { src = wo; dst = Wo; base = blk - 7680; }
  const size_t off = (size_t)base * 2048 + (size_t)threadIdx.x * 8;
  const float4 v0 = *(const float4*)&src[off];
  const float4 v1 = *(const float4*)&src[off + 4];
  short8 o;
  o[0] = (short)f2bf(v0.x); o[1] = (short)f2bf(v0.y);
  o[2] = (short)f2bf(v0.z); o[3] = (short)f2bf(v0.w);
  o[4] = (short)f2bf(v1.x); o[5] = (short)f2bf(v1.y);
  o[6] = (short)f2bf(v1.z); o[7] = (short)f2bf(v1.w);
  *(short8*)&dst[off] = o;
}

// ---------------------------------------------------------------------------
// GEMM core: Y[m0..m0+63, n0..n0+127] = A[.,1024] @ Bt[.,1024]^T + bias
// A row-major bf16, Bt row-major bf16 (reduction dim contiguous in both).
// 256 threads = 4 waves in 2x2; wave tile 32x64; mfma_f32_16x16x32_bf16.
// bias fp32; OutT = ushort_t (bf16 store) or float (fp32 store).
// ---------------------------------------------------------------------------
template <typename OutT>
__device__ __forceinline__ void gemm64x128(
    const ushort_t* __restrict__ A, const ushort_t* __restrict__ Bt,
    const float* __restrict__ bias, OutT* __restrict__ Y, int bm, int bn) {
  constexpr int K = 1024;
  constexpr int NY = 1024;
  __shared__ __align__(16) ushort_t sA[64 * 32];
  __shared__ __align__(16) ushort_t sB[128 * 32];
  const int t = threadIdx.x;
  const int lane = t & 63;
  const int w = t >> 6;
  const int wr = w >> 1, wc = w & 1;
  const int r15 = lane & 15, kh = lane >> 4;  // kh in 0..3
  const int m0 = bm * 64, n0 = bn * 128;

  f32x4 acc[2][4] = {};

  // staging: 16B chunks; A: 256 chunks (1/thread), B: 512 chunks (2/thread)
  const int rowA = t >> 2, ccA = t & 3;
  const ushort_t* gA = A + (size_t)(m0 + rowA) * K + ccA * 8;
  const int rowB0 = t >> 2;
  const int rowB1 = (t + 256) >> 2;
  const int ccB = t & 3;
  const ushort_t* gB0 = Bt + (size_t)(n0 + rowB0) * K + ccB * 8;
  const ushort_t* gB1 = Bt + (size_t)(n0 + rowB1) * K + ccB * 8;
  ushort_t* lA = &sA[t * 8];
  ushort_t* lB0 = &sB[t * 8];
  ushort_t* lB1 = &sB[(t + 256) * 8];

  for (int k0 = 0; k0 < K; k0 += 32) {
    gload16(gA + k0, lA);
    gload16(gB0 + k0, lB0);
    gload16(gB1 + k0, lB1);
    __syncthreads();  // compiler drains vmcnt before s_barrier
    short8 af[2], bfr[4];
#pragma unroll
    for (int m = 0; m < 2; ++m)
      af[m] = *(const short8*)&sA[(wr * 32 + m * 16 + r15) * 32 + kh * 8];
#pragma unroll
    for (int n = 0; n < 4; ++n)
      bfr[n] = *(const short8*)&sB[(wc * 64 + n * 16 + r15) * 32 + kh * 8];
#pragma unroll
    for (int m = 0; m < 2; ++m)
#pragma unroll
      for (int n = 0; n < 4; ++n)
        acc[m][n] = __builtin_amdgcn_mfma_f32_16x16x32_bf16(af[m], bfr[n],
                                                            acc[m][n], 0, 0, 0);
    __syncthreads();
  }

  // epilogue: C/D layout col=lane&15, row=(lane>>4)*4+reg  [verified m89/m91]
  const int orow0 = m0 + wr * 32 + kh * 4;
  const int ocol0 = n0 + wc * 64 + r15;
#pragma unroll
  for (int m = 0; m < 2; ++m) {
#pragma unroll
    for (int n = 0; n < 4; ++n) {
      const int col = ocol0 + n * 16;
      const float bv = bias[col];
#pragma unroll
      for (int j = 0; j < 4; ++j) {
        const int row = orow0 + m * 16 + j;
        const float val = acc[m][n][j] + bv;
        if constexpr (__is_same(OutT, ushort_t))
          Y[(size_t)row * NY + col] = f2bf(val);
        else
          Y[(size_t)row * NY + col] = val;
      }
    }
  }
}

// Fused Q/K/V projections: grid 3*512; tensor select by blockIdx/512.
__global__ __launch_bounds__(256) void proj_qkv_kernel(
    const ushort_t* Xq, const ushort_t* Xk, const ushort_t* Xv,
    const ushort_t* Wq, const ushort_t* Wk, const ushort_t* Wv,
    const float* bq, const float* bk, const float* bv,
    ushort_t* Qb, ushort_t* Kb, ushort_t* Vb) {
  const int blk = blockIdx.x;
  const int tsel = blk >> 9;
  const int rem = blk & 511;
  const int bm = rem >> 3, bn = rem & 7;
  const ushort_t* A = tsel == 0 ? Xq : (tsel == 1 ? Xk : Xv);
  const ushort_t* Bt = tsel == 0 ? Wq : (tsel == 1 ? Wk : Wv);
  const float* bias = tsel == 0 ? bq : (tsel == 1 ? bk : bv);
  ushort_t* Y = tsel == 0 ? Qb : (tsel == 1 ? Kb : Vb);
  gemm64x128<ushort_t>(A, Bt, bias, Y, bm, bn);
}

// Final: out = Q @ Ct[batch]^T + b_o (fp32 output). 64-row blocks never
// straddle the 2048-row batch boundary.
__global__ __launch_bounds__(256) void out_gemm_kernel(
    const ushort_t* Qb, const ushort_t* Ct, const float* bo, float* out) {
  const int blk = blockIdx.x;  // 0..511
  const int bm = blk >> 3, bn = blk & 7;
  const ushort_t* Bt = Ct + (size_t)(bm >> 5) * 1024 * 1024;
  gemm64x128<float>(Qb, Bt, bo, out, bm, bn);
}

// ---------------------------------------------------------------------------
// Mpart[bh][c][d1*64+d2] = sum_{s in chunk c} K[b,s,h*64+d1] * V[b,s,h*64+d2]
// grid 32*16 blocks, 128 s-rows per block. Deterministic partials, no atomics.
// ---------------------------------------------------------------------------
__global__ __launch_bounds__(256) void kv_outer_kernel(
    const ushort_t* __restrict__ Kb, const ushort_t* __restrict__ Vb,
    float* __restrict__ Mpart) {
  const int bh = blockIdx.x >> 4;  // 0..31
  const int c = blockIdx.x & 15;   // chunk
  const int b = bh >> 4, h = bh & 15;
  __shared__ __align__(16) ushort_t sK[128][64];
  __shared__ __align__(16) ushort_t sV[128][64];
  const int t = threadIdx.x;
  const ushort_t* baseK = Kb + (size_t)(b * NS + c * 128) * ND + h * 64;
  const ushort_t* baseV = Vb + (size_t)(b * NS + c * 128) * ND + h * 64;
#pragma unroll
  for (int i = 0; i < 4; ++i) {
    const int ch = t + i * 256;  // 0..1023; 8 chunks of 16B per row
    const int row = ch >> 3, cc = ch & 7;
    *(short8*)&sK[row][cc * 8] = *(const short8*)&baseK[(size_t)row * ND + cc * 8];
    *(short8*)&sV[row][cc * 8] = *(const short8*)&baseV[(size_t)row * ND + cc * 8];
  }
  __syncthreads();
  const int d1 = (t & 15) * 4, d2 = (t >> 4) * 4;
  float acc[4][4] = {};
  for (int s = 0; s < 128; ++s) {
    const uint2 ku = *(const uint2*)&sK[s][d1];
    const uint2 vu = *(const uint2*)&sV[s][d2];
    float kx[4], vx[4];
    kx[0] = __uint_as_float(ku.x << 16);
    kx[1] = __uint_as_float(ku.x & 0xFFFF0000u);
    kx[2] = __uint_as_float(ku.y << 16);
    kx[3] = __uint_as_float(ku.y & 0xFFFF0000u);
    vx[0] = __uint_as_float(vu.x << 16);
    vx[1] = __uint_as_float(vu.x & 0xFFFF0000u);
    vx[2] = __uint_as_float(vu.y << 16);
    vx[3] = __uint_as_float(vu.y & 0xFFFF0000u);
#pragma unroll
    for (int a2 = 0; a2 < 4; ++a2)
#pragma unroll
      for (int b2 = 0; b2 < 4; ++b2) acc[a2][b2] += kx[a2] * vx[b2];
  }
  float* outp = Mpart + ((size_t)bh * 16 + c) * 4096;
#pragma unroll
  for (int a2 = 0; a2 < 4; ++a2)
#pragma unroll
    for (int b2 = 0; b2 < 4; ++b2)
      outp[(d1 + a2) * 64 + (d2 + b2)] = acc[a2][b2];
}

// Mred[bh][e] = (1/8) * sum_c Mpart[bh][c][e]   (1/8 = 1/sqrt(DK))
__global__ __launch_bounds__(256) void reduce_M_kernel(
    const float* __restrict__ Mpart, float* __restrict__ Mred) {
  const int idx = blockIdx.x * 256 + threadIdx.x;  // 0..131071
  const int bh = idx >> 12, e = idx & 4095;
  float s = 0.f;
#pragma unroll
  for (int c = 0; c < 16; ++c) s += Mpart[((size_t)bh * 16 + c) * 4096 + e];
  Mred[idx] = s * 0.125f;
}

// ---------------------------------------------------------------------------
// Ct[b][j][k] = sum_i M[b,h(k)][k&63][i] * w_o[j][h(k)*64+i]  (bf16, stored
// transposed so the final GEMM sees the Bt layout). grid 2*16*16: (b,h,jb)
// ---------------------------------------------------------------------------
__global__ __launch_bounds__(256) void build_C_kernel(
    const float* __restrict__ Mred, const ushort_t* __restrict__ Wo,
    ushort_t* __restrict__ Ct) {
  const int blk = blockIdx.x;
  const int b = blk >> 8, h = (blk >> 4) & 15, jb = blk & 15;
  __shared__ float sM[64][65];  // +1 pad: strided reads conflict-free
  __shared__ __align__(16) ushort_t sW[64][72];
  const int t = threadIdx.x;
  const float* Mp = Mred + (size_t)(b * 16 + h) * 4096;
#pragma unroll
  for (int i = 0; i < 16; ++i) {
    const int e = t + i * 256;
    sM[e >> 6][e & 63] = Mp[e];
  }
  const int j0 = jb * 64;
#pragma unroll
  for (int i = 0; i < 2; ++i) {
    const int ch = t + i * 256;
    const int row = ch >> 3, cc = ch & 7;
    *(short8*)&sW[row][cc * 8] =
        *(const short8*)&Wo[(size_t)(j0 + row) * ND + h * 64 + cc * 8];
  }
  __syncthreads();
  const int kk = (t & 15) * 4, jj = (t >> 4) * 4;
  float acc[4][4] = {};
  for (int i = 0; i < 64; ++i) {
    float mv[4], wv[4];
#pragma unroll
    for (int a2 = 0; a2 < 4; ++a2) mv[a2] = sM[kk + a2][i];
#pragma unroll
    for (int b2 = 0; b2 < 4; ++b2) wv[b2] = bf2f(sW[jj + b2][i]);
#pragma unroll
    for (int a2 = 0; a2 < 4; ++a2)
#pragma unroll
      for (int b2 = 0; b2 < 4; ++b2) acc[a2][b2] += mv[a2] * wv[b2];
  }
#pragma unroll
  for (int a2 = 0; a2 < 4; ++a2)
#pragma unroll
    for (int b2 = 0; b2 < 4; ++b2)
      Ct[((size_t)b * ND + j0 + jj + b2) * ND + h * 64 + kk + a2] =
          f2bf(acc[a2][b2]);
}

// ---------------------------------------------------------------------------
extern "C" void kernel_launch(void* const* d_in, const int* in_sizes, int n_in,
                              void* d_out, int out_size, void* d_ws,
                              size_t ws_size, hipStream_t stream) {
  (void)in_sizes; (void)n_in; (void)out_size; (void)ws_size;
  const float* q = (const float*)d_in[0];
  const float* k = (const float*)d_in[1];
  const float* v = (const float*)d_in[2];
  const float* wq = (const float*)d_in[3];
  const float* bq = (const float*)d_in[4];
  const float* wk = (const float*)d_in[5];
  const float* bk = (const float*)d_in[6];
  const float* wv = (const float*)d_in[7];
  const float* bv = (const float*)d_in[8];
  const float* wo = (const float*)d_in[9];
  const float* bo = (const float*)d_in[10];
  float* out = (float*)d_out;

  const size_t MB = 1048576;
  char* ws = (char*)d_ws;
  // phase 1 buffers (bf16 inputs)
  ushort_t* Xq = (ushort_t*)(ws + 0 * MB);    // 8 MB [4096,1024] bf16
  ushort_t* Xk = (ushort_t*)(ws + 8 * MB);    // 8 MB
  ushort_t* Xv = (ushort_t*)(ws + 16 * MB);   // 8 MB
  ushort_t* Wq = (ushort_t*)(ws + 24 * MB);   // 2 MB [1024,1024] bf16
  ushort_t* Wk = (ushort_t*)(ws + 26 * MB);   // 2 MB
  ushort_t* Wv = (ushort_t*)(ws + 28 * MB);   // 2 MB
  ushort_t* Wo = (ushort_t*)(ws + 30 * MB);   // 2 MB
  ushort_t* Qb = (ushort_t*)(ws + 32 * MB);   // 8 MB
  ushort_t* Kb = (ushort_t*)(ws + 40 * MB);   // 8 MB
  ushort_t* Vb = (ushort_t*)(ws + 48 * MB);   // 8 MB (total 56 MB)
  // phase 2 overlays (Xq/Xk dead after proj_qkv)
  float* Mpart = (float*)(ws + 0 * MB);              // 8 MB [32][16][4096] f32
  float* Mred = (float*)(ws + 8 * MB);               // 512 KB [32][4096] f32
  ushort_t* Ct = (ushort_t*)(ws + 8 * MB + 524288);  // 4 MB [2][1024][1024] bf16

  hipLaunchKernelGGL(convert_kernel, dim3(8192), dim3(256), 0, stream, q, k, v,
                     wq, wk, wv, wo, Xq, Xk, Xv, Wq, Wk, Wv, Wo);
  hipLaunchKernelGGL(proj_qkv_kernel, dim3(1536), dim3(256), 0, stream, Xq, Xk,
                     Xv, Wq, Wk, Wv, bq, bk, bv, Qb, Kb, Vb);
  hipLaunchKernelGGL(kv_outer_kernel, dim3(512), dim3(256), 0, stream, Kb, Vb,
                     Mpart);
  hipLaunchKernelGGL(reduce_M_kernel, dim3(512), dim3(256), 0, stream, Mpart,
                     Mred);
  hipLaunchKernelGGL(build_C_kernel, dim3(512), dim3(256), 0, stream, Mred, Wo,
                     Ct);
  hipLaunchKernelGGL(out_gemm_kernel, dim3(512), dim3(256), 0, stream, Qb, Ct,
                     bo, out);
}

// Round 4
// 218.060 us; speedup vs baseline: 1.0072x; 1.0072x over previous
//
#include <hip/hip_runtime.h>
#include <hip/hip_bf16.h>

typedef unsigned short ushort_t;
typedef unsigned int uint32;
typedef __attribute__((ext_vector_type(8))) short short8;
typedef __attribute__((ext_vector_type(4))) float f32x4;

// Problem constants: B=2, S=2048, D=1024, H=16, DK=64
#define NB 2
#define NS 2048
#define ND 1024
#define NH 16

__device__ __forceinline__ float bf2f(ushort_t u) {
  return __uint_as_float(((uint32)u) << 16);
}
__device__ __forceinline__ ushort_t f2bf(float x) {
  uint32 u = __float_as_uint(x);
  uint32 r = u + 0x7FFFu + ((u >> 16) & 1u);  // RNE
  return (ushort_t)(r >> 16);
}

__device__ __forceinline__ void gload16(const void* g, void* l) {
  __builtin_amdgcn_global_load_lds(
      (const __attribute__((address_space(1))) void*)g,
      (__attribute__((address_space(3))) void*)l, 16, 0, 0);
}

// ---------------------------------------------------------------------------
// fp32 -> bf16 convert: 7 segments (q,k,v: 2048 blocks each; 4 weights: 512
// blocks each). Each block converts 2048 elements (256 thr x 8).
// ---------------------------------------------------------------------------
__global__ __launch_bounds__(256) void convert_kernel(
    const float* q, const float* k, const float* v, const float* wq,
    const float* wk, const float* wv, const float* wo, ushort_t* Xq,
    ushort_t* Xk, ushort_t* Xv, ushort_t* Wq, ushort_t* Wk, ushort_t* Wv,
    ushort_t* Wo) {
  const int blk = blockIdx.x;
  const float* src;
  ushort_t* dst;
  int base;
  if (blk < 2048) { src = q; dst = Xq; base = blk; }
  else if (blk < 4096) { src = k; dst = Xk; base = blk - 2048; }
  else if (blk < 6144) { src = v; dst = Xv; base = blk - 4096; }
  else if (blk < 6656) { src = wq; dst = Wq; base = blk - 6144; }
  else if (blk < 7168) { src = wk; dst = Wk; base = blk - 6656; }
  else if (blk < 7680) { src = wv; dst = Wv; base = blk - 7168; }
  else { src = wo; dst = Wo; base = blk - 7680; }
  const size_t off = (size_t)base * 2048 + (size_t)threadIdx.x * 8;
  const float4 v0 = *(const float4*)&src[off];
  const float4 v1 = *(const float4*)&src[off + 4];
  short8 o;
  o[0] = (short)f2bf(v0.x); o[1] = (short)f2bf(v0.y);
  o[2] = (short)f2bf(v0.z); o[3] = (short)f2bf(v0.w);
  o[4] = (short)f2bf(v1.x); o[5] = (short)f2bf(v1.y);
  o[6] = (short)f2bf(v1.z); o[7] = (short)f2bf(v1.w);
  *(short8*)&dst[off] = o;
}

// ---------------------------------------------------------------------------
// GEMM core (m97 structure): Y[128,128] tile = A[.,1024] @ Bt[.,1024]^T + bias
// A,Bt row-major bf16, K=1024 contiguous in both. 256 thr = 4 waves in 2x2;
// wave tile 64x64 = 4x4 mfma_f32_16x16x32_bf16 fragments; BK=32;
// global_load_lds width 16 (4 chunks/thread/K-step). LDS 16 KB.
// ---------------------------------------------------------------------------
template <typename OutT>
__device__ __forceinline__ void gemm128x128(
    const ushort_t* __restrict__ A, const ushort_t* __restrict__ Bt,
    const float* __restrict__ bias, OutT* __restrict__ Y, int bm, int bn) {
  constexpr int K = 1024;
  constexpr int NY = 1024;
  __shared__ __align__(16) ushort_t sA[128 * 32];
  __shared__ __align__(16) ushort_t sB[128 * 32];
  const int t = threadIdx.x;
  const int lane = t & 63;
  const int w = t >> 6;
  const int wr = w >> 1, wc = w & 1;
  const int r15 = lane & 15, kh = lane >> 4;  // kh in 0..3
  const int m0 = bm * 128, n0 = bn * 128;

  f32x4 acc[4][4] = {};

  // staging: 16B chunks, layout row-major [128][32]; chunk c: row=c>>2, cc=c&3
  // each thread owns chunks t and t+256 for both A and B.
  const int row0 = t >> 2, cc8 = (t & 3) * 8;
  const ushort_t* gA0 = A + (size_t)(m0 + row0) * K + cc8;
  const ushort_t* gA1 = A + (size_t)(m0 + row0 + 64) * K + cc8;
  const ushort_t* gB0 = Bt + (size_t)(n0 + row0) * K + cc8;
  const ushort_t* gB1 = Bt + (size_t)(n0 + row0 + 64) * K + cc8;
  ushort_t* lA0 = &sA[t * 8];
  ushort_t* lA1 = &sA[(t + 256) * 8];
  ushort_t* lB0 = &sB[t * 8];
  ushort_t* lB1 = &sB[(t + 256) * 8];

  for (int k0 = 0; k0 < K; k0 += 32) {
    gload16(gA0 + k0, lA0);
    gload16(gA1 + k0, lA1);
    gload16(gB0 + k0, lB0);
    gload16(gB1 + k0, lB1);
    __syncthreads();  // compiler drains vmcnt before s_barrier
    short8 af[4], bfr[4];
#pragma unroll
    for (int m = 0; m < 4; ++m)
      af[m] = *(const short8*)&sA[(wr * 64 + m * 16 + r15) * 32 + kh * 8];
#pragma unroll
    for (int n = 0; n < 4; ++n)
      bfr[n] = *(const short8*)&sB[(wc * 64 + n * 16 + r15) * 32 + kh * 8];
#pragma unroll
    for (int m = 0; m < 4; ++m)
#pragma unroll
      for (int n = 0; n < 4; ++n)
        acc[m][n] = __builtin_amdgcn_mfma_f32_16x16x32_bf16(af[m], bfr[n],
                                                            acc[m][n], 0, 0, 0);
    __syncthreads();
  }

  // epilogue: C/D layout col=lane&15, row=(lane>>4)*4+reg  [verified m89/m91]
  const int orow0 = m0 + wr * 64 + kh * 4;
  const int ocol0 = n0 + wc * 64 + r15;
#pragma unroll
  for (int m = 0; m < 4; ++m) {
#pragma unroll
    for (int n = 0; n < 4; ++n) {
      const int col = ocol0 + n * 16;
      const float bv = bias[col];
#pragma unroll
      for (int j = 0; j < 4; ++j) {
        const int row = orow0 + m * 16 + j;
        const float val = acc[m][n][j] + bv;
        if constexpr (__is_same(OutT, ushort_t))
          Y[(size_t)row * NY + col] = f2bf(val);
        else
          Y[(size_t)row * NY + col] = val;
      }
    }
  }
}

// Fused Q/K/V projections: grid 3*256; tensor select by blockIdx/256.
__global__ __launch_bounds__(256) void proj_qkv_kernel(
    const ushort_t* Xq, const ushort_t* Xk, const ushort_t* Xv,
    const ushort_t* Wq, const ushort_t* Wk, const ushort_t* Wv,
    const float* bq, const float* bk, const float* bv,
    ushort_t* Qb, ushort_t* Kb, ushort_t* Vb) {
  const int blk = blockIdx.x;
  const int tsel = blk >> 8;
  const int rem = blk & 255;
  const int bm = rem >> 3, bn = rem & 7;  // bm 0..31, bn 0..7
  const ushort_t* A = tsel == 0 ? Xq : (tsel == 1 ? Xk : Xv);
  const ushort_t* Bt = tsel == 0 ? Wq : (tsel == 1 ? Wk : Wv);
  const float* bias = tsel == 0 ? bq : (tsel == 1 ? bk : bv);
  ushort_t* Y = tsel == 0 ? Qb : (tsel == 1 ? Kb : Vb);
  gemm128x128<ushort_t>(A, Bt, bias, Y, bm, bn);
}

// Final: out = Q @ Ct[batch]^T + b_o (fp32 output). 128-row blocks never
// straddle the 2048-row batch boundary (16 blocks per batch).
__global__ __launch_bounds__(256) void out_gemm_kernel(
    const ushort_t* Qb, const ushort_t* Ct, const float* bo, float* out) {
  const int blk = blockIdx.x;  // 0..255
  const int bm = blk >> 3, bn = blk & 7;
  const ushort_t* Bt = Ct + (size_t)(bm >> 4) * 1024 * 1024;
  gemm128x128<float>(Qb, Bt, bo, out, bm, bn);
}

// ---------------------------------------------------------------------------
// Mpart[bh][c][d1*64+d2] = sum_{s in chunk c} K[b,s,h*64+d1] * V[b,s,h*64+d2]
// grid 32*16 blocks, 128 s-rows per block. Deterministic partials, no atomics.
// ---------------------------------------------------------------------------
__global__ __launch_bounds__(256) void kv_outer_kernel(
    const ushort_t* __restrict__ Kb, const ushort_t* __restrict__ Vb,
    float* __restrict__ Mpart) {
  const int bh = blockIdx.x >> 4;  // 0..31
  const int c = blockIdx.x & 15;   // chunk
  const int b = bh >> 4, h = bh & 15;
  __shared__ __align__(16) ushort_t sK[128][64];
  __shared__ __align__(16) ushort_t sV[128][64];
  const int t = threadIdx.x;
  const ushort_t* baseK = Kb + (size_t)(b * NS + c * 128) * ND + h * 64;
  const ushort_t* baseV = Vb + (size_t)(b * NS + c * 128) * ND + h * 64;
#pragma unroll
  for (int i = 0; i < 4; ++i) {
    const int ch = t + i * 256;  // 0..1023; 8 chunks of 16B per row
    const int row = ch >> 3, cc = ch & 7;
    *(short8*)&sK[row][cc * 8] = *(const short8*)&baseK[(size_t)row * ND + cc * 8];
    *(short8*)&sV[row][cc * 8] = *(const short8*)&baseV[(size_t)row * ND + cc * 8];
  }
  __syncthreads();
  const int d1 = (t & 15) * 4, d2 = (t >> 4) * 4;
  float acc[4][4] = {};
  for (int s = 0; s < 128; ++s) {
    const uint2 ku = *(const uint2*)&sK[s][d1];
    const uint2 vu = *(const uint2*)&sV[s][d2];
    float kx[4], vx[4];
    kx[0] = __uint_as_float(ku.x << 16);
    kx[1] = __uint_as_float(ku.x & 0xFFFF0000u);
    kx[2] = __uint_as_float(ku.y << 16);
    kx[3] = __uint_as_float(ku.y & 0xFFFF0000u);
    vx[0] = __uint_as_float(vu.x << 16);
    vx[1] = __uint_as_float(vu.x & 0xFFFF0000u);
    vx[2] = __uint_as_float(vu.y << 16);
    vx[3] = __uint_as_float(vu.y & 0xFFFF0000u);
#pragma unroll
    for (int a2 = 0; a2 < 4; ++a2)
#pragma unroll
      for (int b2 = 0; b2 < 4; ++b2) acc[a2][b2] += kx[a2] * vx[b2];
  }
  float* outp = Mpart + ((size_t)bh * 16 + c) * 4096;
#pragma unroll
  for (int a2 = 0; a2 < 4; ++a2)
#pragma unroll
    for (int b2 = 0; b2 < 4; ++b2)
      outp[(d1 + a2) * 64 + (d2 + b2)] = acc[a2][b2];
}

// Mred[bh][e] = (1/8) * sum_c Mpart[bh][c][e]   (1/8 = 1/sqrt(DK))
__global__ __launch_bounds__(256) void reduce_M_kernel(
    const float* __restrict__ Mpart, float* __restrict__ Mred) {
  const int idx = blockIdx.x * 256 + threadIdx.x;  // 0..131071
  const int bh = idx >> 12, e = idx & 4095;
  float s = 0.f;
#pragma unroll
  for (int c = 0; c < 16; ++c) s += Mpart[((size_t)bh * 16 + c) * 4096 + e];
  Mred[idx] = s * 0.125f;
}

// ---------------------------------------------------------------------------
// Ct[b][j][k] = sum_i M[b,h(k)][k&63][i] * w_o[j][h(k)*64+i]  (bf16, stored
// transposed so the final GEMM sees the Bt layout). grid 2*16*16: (b,h,jb)
// ---------------------------------------------------------------------------
__global__ __launch_bounds__(256) void build_C_kernel(
    const float* __restrict__ Mred, const ushort_t* __restrict__ Wo,
    ushort_t* __restrict__ Ct) {
  const int blk = blockIdx.x;
  const int b = blk >> 8, h = (blk >> 4) & 15, jb = blk & 15;
  __shared__ float sM[64][65];  // +1 pad: strided reads conflict-free
  __shared__ __align__(16) ushort_t sW[64][72];
  const int t = threadIdx.x;
  const float* Mp = Mred + (size_t)(b * 16 + h) * 4096;
#pragma unroll
  for (int i = 0; i < 16; ++i) {
    const int e = t + i * 256;
    sM[e >> 6][e & 63] = Mp[e];
  }
  const int j0 = jb * 64;
#pragma unroll
  for (int i = 0; i < 2; ++i) {
    const int ch = t + i * 256;
    const int row = ch >> 3, cc = ch & 7;
    *(short8*)&sW[row][cc * 8] =
        *(const short8*)&Wo[(size_t)(j0 + row) * ND + h * 64 + cc * 8];
  }
  __syncthreads();
  const int kk = (t & 15) * 4, jj = (t >> 4) * 4;
  float acc[4][4] = {};
  for (int i = 0; i < 64; ++i) {
    float mv[4], wv[4];
#pragma unroll
    for (int a2 = 0; a2 < 4; ++a2) mv[a2] = sM[kk + a2][i];
#pragma unroll
    for (int b2 = 0; b2 < 4; ++b2) wv[b2] = bf2f(sW[jj + b2][i]);
#pragma unroll
    for (int a2 = 0; a2 < 4; ++a2)
#pragma unroll
      for (int b2 = 0; b2 < 4; ++b2) acc[a2][b2] += mv[a2] * wv[b2];
  }
#pragma unroll
  for (int a2 = 0; a2 < 4; ++a2)
#pragma unroll
    for (int b2 = 0; b2 < 4; ++b2)
      Ct[((size_t)b * ND + j0 + jj + b2) * ND + h * 64 + kk + a2] =
          f2bf(acc[a2][b2]);
}

// ---------------------------------------------------------------------------
extern "C" void kernel_launch(void* const* d_in, const int* in_sizes, int n_in,
                              void* d_out, int out_size, void* d_ws,
                              size_t ws_size, hipStream_t stream) {
  (void)in_sizes; (void)n_in; (void)out_size; (void)ws_size;
  const float* q = (const float*)d_in[0];
  const float* k = (const float*)d_in[1];
  const float* v = (const float*)d_in[2];
  const float* wq = (const float*)d_in[3];
  const float* bq = (const float*)d_in[4];
  const float* wk = (const float*)d_in[5];
  const float* bk = (const float*)d_in[6];
  const float* wv = (const float*)d_in[7];
  const float* bv = (const float*)d_in[8];
  const float* wo = (const float*)d_in[9];
  const float* bo = (const float*)d_in[10];
  float* out = (float*)d_out;

  const size_t MB = 1048576;
  char* ws = (char*)d_ws;
  // phase 1 buffers (bf16 inputs)
  ushort_t* Xq = (ushort_t*)(ws + 0 * MB);    // 8 MB [4096,1024] bf16
  ushort_t* Xk = (ushort_t*)(ws + 8 * MB);    // 8 MB
  ushort_t* Xv = (ushort_t*)(ws + 16 * MB);   // 8 MB
  ushort_t* Wq = (ushort_t*)(ws + 24 * MB);   // 2 MB [1024,1024] bf16
  ushort_t* Wk = (ushort_t*)(ws + 26 * MB);   // 2 MB
  ushort_t* Wv = (ushort_t*)(ws + 28 * MB);   // 2 MB
  ushort_t* Wo = (ushort_t*)(ws + 30 * MB);   // 2 MB
  ushort_t* Qb = (ushort_t*)(ws + 32 * MB);   // 8 MB
  ushort_t* Kb = (ushort_t*)(ws + 40 * MB);   // 8 MB
  ushort_t* Vb = (ushort_t*)(ws + 48 * MB);   // 8 MB (total 56 MB)
  // phase 2 overlays (Xq/Xk dead after proj_qkv)
  float* Mpart = (float*)(ws + 0 * MB);              // 8 MB [32][16][4096] f32
  float* Mred = (float*)(ws + 8 * MB);               // 512 KB [32][4096] f32
  ushort_t* Ct = (ushort_t*)(ws + 8 * MB + 524288);  // 4 MB [2][1024][1024] bf16

  hipLaunchKernelGGL(convert_kernel, dim3(8192), dim3(256), 0, stream, q, k, v,
                     wq, wk, wv, wo, Xq, Xk, Xv, Wq, Wk, Wv, Wo);
  hipLaunchKernelGGL(proj_qkv_kernel, dim3(768), dim3(256), 0, stream, Xq, Xk,
                     Xv, Wq, Wk, Wv, bq, bk, bv, Qb, Kb, Vb);
  hipLaunchKernelGGL(kv_outer_kernel, dim3(512), dim3(256), 0, stream, Kb, Vb,
                     Mpart);
  hipLaunchKernelGGL(reduce_M_kernel, dim3(512), dim3(256), 0, stream, Mpart,
                     Mred);
  hipLaunchKernelGGL(build_C_kernel, dim3(512), dim3(256), 0, stream, Mred, Wo,
                     Ct);
  hipLaunchKernelGGL(out_gemm_kernel, dim3(256), dim3(256), 0, stream, Qb, Ct,
                     bo, out);
}

// Round 5
// 205.893 us; speedup vs baseline: 1.0667x; 1.0591x over previous
//
#include <hip/hip_runtime.h>
#include <hip/hip_bf16.h>

typedef unsigned short ushort_t;
typedef unsigned int uint32;
typedef __attribute__((ext_vector_type(8))) short short8;
typedef __attribute__((ext_vector_type(4))) float f32x4;

// Problem constants: B=2, S=2048, D=1024, H=16, DK=64
#define NB 2
#define NS 2048
#define ND 1024
#define NH 16

__device__ __forceinline__ float bf2f(ushort_t u) {
  return __uint_as_float(((uint32)u) << 16);
}
__device__ __forceinline__ ushort_t f2bf(float x) {
  uint32 u = __float_as_uint(x);
  uint32 r = u + 0x7FFFu + ((u >> 16) & 1u);  // RNE
  return (ushort_t)(r >> 16);
}

__device__ __forceinline__ void gload16(const void* g, void* l) {
  __builtin_amdgcn_global_load_lds(
      (const __attribute__((address_space(1))) void*)g,
      (__attribute__((address_space(3))) void*)l, 16, 0, 0);
}

// ---------------------------------------------------------------------------
// fp32 -> bf16 convert: 7 segments (q,k,v: 2048 blocks each; 4 weights: 512
// blocks each). Each block converts 2048 elements (256 thr x 8).
// ---------------------------------------------------------------------------
__global__ __launch_bounds__(256) void convert_kernel(
    const float* q, const float* k, const float* v, const float* wq,
    const float* wk, const float* wv, const float* wo, ushort_t* Xq,
    ushort_t* Xk, ushort_t* Xv, ushort_t* Wq, ushort_t* Wk, ushort_t* Wv,
    ushort_t* Wo) {
  const int blk = blockIdx.x;
  const float* src;
  ushort_t* dst;
  int base;
  if (blk < 2048) { src = q; dst = Xq; base = blk; }
  else if (blk < 4096) { src = k; dst = Xk; base = blk - 2048; }
  else if (blk < 6144) { src = v; dst = Xv; base = blk - 4096; }
  else if (blk < 6656) { src = wq; dst = Wq; base = blk - 6144; }
  else if (blk < 7168) { src = wk; dst = Wk; base = blk - 6656; }
  else if (blk < 7680) { src = wv; dst = Wv; base = blk - 7168; }
  else { src = wo; dst = Wo; base = blk - 7680; }
  const size_t off = (size_t)base * 2048 + (size_t)threadIdx.x * 8;
  const float4 v0 = *(const float4*)&src[off];
  const float4 v1 = *(const float4*)&src[off + 4];
  short8 o;
  o[0] = (short)f2bf(v0.x); o[1] = (short)f2bf(v0.y);
  o[2] = (short)f2bf(v0.z); o[3] = (short)f2bf(v0.w);
  o[4] = (short)f2bf(v1.x); o[5] = (short)f2bf(v1.y);
  o[6] = (short)f2bf(v1.z); o[7] = (short)f2bf(v1.w);
  *(short8*)&dst[off] = o;
}

// ---------------------------------------------------------------------------
// GEMM core (m97 structure): Y[128,128] tile = A[.,1024] @ Bt[.,1024]^T + bias
// 256 thr = 4 waves 2x2; wave tile 64x64 = 4x4 mfma_f32_16x16x32_bf16; BK=32.
// ---------------------------------------------------------------------------
template <typename OutT>
__device__ __forceinline__ void gemm128x128(
    const ushort_t* __restrict__ A, const ushort_t* __restrict__ Bt,
    const float* __restrict__ bias, OutT* __restrict__ Y, int bm, int bn) {
  constexpr int K = 1024;
  constexpr int NY = 1024;
  __shared__ __align__(16) ushort_t sA[128 * 32];
  __shared__ __align__(16) ushort_t sB[128 * 32];
  const int t = threadIdx.x;
  const int lane = t & 63;
  const int w = t >> 6;
  const int wr = w >> 1, wc = w & 1;
  const int r15 = lane & 15, kh = lane >> 4;  // kh in 0..3
  const int m0 = bm * 128, n0 = bn * 128;

  f32x4 acc[4][4] = {};

  const int row0 = t >> 2, cc8 = (t & 3) * 8;
  const ushort_t* gA0 = A + (size_t)(m0 + row0) * K + cc8;
  const ushort_t* gA1 = A + (size_t)(m0 + row0 + 64) * K + cc8;
  const ushort_t* gB0 = Bt + (size_t)(n0 + row0) * K + cc8;
  const ushort_t* gB1 = Bt + (size_t)(n0 + row0 + 64) * K + cc8;
  ushort_t* lA0 = &sA[t * 8];
  ushort_t* lA1 = &sA[(t + 256) * 8];
  ushort_t* lB0 = &sB[t * 8];
  ushort_t* lB1 = &sB[(t + 256) * 8];

  for (int k0 = 0; k0 < K; k0 += 32) {
    gload16(gA0 + k0, lA0);
    gload16(gA1 + k0, lA1);
    gload16(gB0 + k0, lB0);
    gload16(gB1 + k0, lB1);
    __syncthreads();
    short8 af[4], bfr[4];
#pragma unroll
    for (int m = 0; m < 4; ++m)
      af[m] = *(const short8*)&sA[(wr * 64 + m * 16 + r15) * 32 + kh * 8];
#pragma unroll
    for (int n = 0; n < 4; ++n)
      bfr[n] = *(const short8*)&sB[(wc * 64 + n * 16 + r15) * 32 + kh * 8];
#pragma unroll
    for (int m = 0; m < 4; ++m)
#pragma unroll
      for (int n = 0; n < 4; ++n)
        acc[m][n] = __builtin_amdgcn_mfma_f32_16x16x32_bf16(af[m], bfr[n],
                                                            acc[m][n], 0, 0, 0);
    __syncthreads();
  }

  const int orow0 = m0 + wr * 64 + kh * 4;
  const int ocol0 = n0 + wc * 64 + r15;
#pragma unroll
  for (int m = 0; m < 4; ++m) {
#pragma unroll
    for (int n = 0; n < 4; ++n) {
      const int col = ocol0 + n * 16;
      const float bv = bias[col];
#pragma unroll
      for (int j = 0; j < 4; ++j) {
        const int row = orow0 + m * 16 + j;
        const float val = acc[m][n][j] + bv;
        if constexpr (__is_same(OutT, ushort_t))
          Y[(size_t)row * NY + col] = f2bf(val);
        else
          Y[(size_t)row * NY + col] = val;
      }
    }
  }
}

// ---------------------------------------------------------------------------
// GEMM core 64x128 (higher TLP variant for the latency-bound final GEMM).
// 256 thr = 4 waves 2x2; wave tile 32x64 = 2x4 fragments; BK=32.
// ---------------------------------------------------------------------------
template <typename OutT>
__device__ __forceinline__ void gemm64x128(
    const ushort_t* __restrict__ A, const ushort_t* __restrict__ Bt,
    const float* __restrict__ bias, OutT* __restrict__ Y, int bm, int bn) {
  constexpr int K = 1024;
  constexpr int NY = 1024;
  __shared__ __align__(16) ushort_t sA[64 * 32];
  __shared__ __align__(16) ushort_t sB[128 * 32];
  const int t = threadIdx.x;
  const int lane = t & 63;
  const int w = t >> 6;
  const int wr = w >> 1, wc = w & 1;
  const int r15 = lane & 15, kh = lane >> 4;
  const int m0 = bm * 64, n0 = bn * 128;

  f32x4 acc[2][4] = {};

  const int rowA = t >> 2, cc8 = (t & 3) * 8;
  const ushort_t* gA = A + (size_t)(m0 + rowA) * K + cc8;
  const ushort_t* gB0 = Bt + (size_t)(n0 + rowA) * K + cc8;
  const ushort_t* gB1 = Bt + (size_t)(n0 + rowA + 64) * K + cc8;
  ushort_t* lA = &sA[t * 8];
  ushort_t* lB0 = &sB[t * 8];
  ushort_t* lB1 = &sB[(t + 256) * 8];

  for (int k0 = 0; k0 < K; k0 += 32) {
    gload16(gA + k0, lA);
    gload16(gB0 + k0, lB0);
    gload16(gB1 + k0, lB1);
    __syncthreads();
    short8 af[2], bfr[4];
#pragma unroll
    for (int m = 0; m < 2; ++m)
      af[m] = *(const short8*)&sA[(wr * 32 + m * 16 + r15) * 32 + kh * 8];
#pragma unroll
    for (int n = 0; n < 4; ++n)
      bfr[n] = *(const short8*)&sB[(wc * 64 + n * 16 + r15) * 32 + kh * 8];
#pragma unroll
    for (int m = 0; m < 2; ++m)
#pragma unroll
      for (int n = 0; n < 4; ++n)
        acc[m][n] = __builtin_amdgcn_mfma_f32_16x16x32_bf16(af[m], bfr[n],
                                                            acc[m][n], 0, 0, 0);
    __syncthreads();
  }

  const int orow0 = m0 + wr * 32 + kh * 4;
  const int ocol0 = n0 + wc * 64 + r15;
#pragma unroll
  for (int m = 0; m < 2; ++m) {
#pragma unroll
    for (int n = 0; n < 4; ++n) {
      const int col = ocol0 + n * 16;
      const float bv = bias[col];
#pragma unroll
      for (int j = 0; j < 4; ++j) {
        const int row = orow0 + m * 16 + j;
        const float val = acc[m][n][j] + bv;
        if constexpr (__is_same(OutT, ushort_t))
          Y[(size_t)row * NY + col] = f2bf(val);
        else
          Y[(size_t)row * NY + col] = val;
      }
    }
  }
}

// Fused Q/K/V projections: grid 3*256. T1 XCD-chunked swizzle within each
// 256-block tensor group: XCD x gets 4 contiguous bm-panels x 8 bn ->
// per-XCD L2 working set = 1 MB A + 2 MB B < 4 MB.
__global__ __launch_bounds__(256) void proj_qkv_kernel(
    const ushort_t* Xq, const ushort_t* Xk, const ushort_t* Xv,
    const ushort_t* Wq, const ushort_t* Wk, const ushort_t* Wv,
    const float* bq, const float* bk, const float* bv,
    ushort_t* Qb, ushort_t* Kb, ushort_t* Vb) {
  const int blk = blockIdx.x;
  const int tsel = blk >> 8;
  int rem = blk & 255;
  rem = (rem & 7) * 32 + (rem >> 3);  // XCD-chunked (256 % 8 == 0, bijective)
  const int bm = rem >> 3, bn = rem & 7;  // bm 0..31, bn 0..7
  const ushort_t* A = tsel == 0 ? Xq : (tsel == 1 ? Xk : Xv);
  const ushort_t* Bt = tsel == 0 ? Wq : (tsel == 1 ? Wk : Wv);
  const float* bias = tsel == 0 ? bq : (tsel == 1 ? bk : bv);
  ushort_t* Y = tsel == 0 ? Qb : (tsel == 1 ? Kb : Vb);
  gemm128x128<ushort_t>(A, Bt, bias, Y, bm, bn);
}

// Final: out = Q @ Ct[batch]^T + b_o (fp32). 64x128 tiles, grid 512
// (2 blocks/CU), XCD-chunked swizzle; 8 bm-panels per chunk never straddle
// the batch boundary (8 | 32).
__global__ __launch_bounds__(256) void out_gemm_kernel(
    const ushort_t* Qb, const ushort_t* Ct, const float* bo, float* out) {
  int blk = blockIdx.x;  // 0..511
  blk = (blk & 7) * 64 + (blk >> 3);  // XCD-chunked (512 % 8 == 0)
  const int bm = blk >> 3, bn = blk & 7;  // bm 0..63 (64-row tiles)
  const ushort_t* Bt = Ct + (size_t)(bm >> 5) * 1024 * 1024;
  gemm64x128<float>(Qb, Bt, bo, out, bm, bn);
}

// ---------------------------------------------------------------------------
// Mpart[bh][c][d1*64+d2] = sum_{s in chunk c} K[b,s,h*64+d1] * V[b,s,h*64+d2]
// ---------------------------------------------------------------------------
__global__ __launch_bounds__(256) void kv_outer_kernel(
    const ushort_t* __restrict__ Kb, const ushort_t* __restrict__ Vb,
    float* __restrict__ Mpart) {
  const int bh = blockIdx.x >> 4;  // 0..31
  const int c = blockIdx.x & 15;   // chunk
  const int b = bh >> 4, h = bh & 15;
  __shared__ __align__(16) ushort_t sK[128][64];
  __shared__ __align__(16) ushort_t sV[128][64];
  const int t = threadIdx.x;
  const ushort_t* baseK = Kb + (size_t)(b * NS + c * 128) * ND + h * 64;
  const ushort_t* baseV = Vb + (size_t)(b * NS + c * 128) * ND + h * 64;
#pragma unroll
  for (int i = 0; i < 4; ++i) {
    const int ch = t + i * 256;
    const int row = ch >> 3, cc = ch & 7;
    *(short8*)&sK[row][cc * 8] = *(const short8*)&baseK[(size_t)row * ND + cc * 8];
    *(short8*)&sV[row][cc * 8] = *(const short8*)&baseV[(size_t)row * ND + cc * 8];
  }
  __syncthreads();
  const int d1 = (t & 15) * 4, d2 = (t >> 4) * 4;
  float acc[4][4] = {};
  for (int s = 0; s < 128; ++s) {
    const uint2 ku = *(const uint2*)&sK[s][d1];
    const uint2 vu = *(const uint2*)&sV[s][d2];
    float kx[4], vx[4];
    kx[0] = __uint_as_float(ku.x << 16);
    kx[1] = __uint_as_float(ku.x & 0xFFFF0000u);
    kx[2] = __uint_as_float(ku.y << 16);
    kx[3] = __uint_as_float(ku.y & 0xFFFF0000u);
    vx[0] = __uint_as_float(vu.x << 16);
    vx[1] = __uint_as_float(vu.x & 0xFFFF0000u);
    vx[2] = __uint_as_float(vu.y << 16);
    vx[3] = __uint_as_float(vu.y & 0xFFFF0000u);
#pragma unroll
    for (int a2 = 0; a2 < 4; ++a2)
#pragma unroll
      for (int b2 = 0; b2 < 4; ++b2) acc[a2][b2] += kx[a2] * vx[b2];
  }
  float* outp = Mpart + ((size_t)bh * 16 + c) * 4096;
#pragma unroll
  for (int a2 = 0; a2 < 4; ++a2)
#pragma unroll
    for (int b2 = 0; b2 < 4; ++b2)
      outp[(d1 + a2) * 64 + (d2 + b2)] = acc[a2][b2];
}

// Mred[bh][e] = (1/8) * sum_c Mpart[bh][c][e]
__global__ __launch_bounds__(256) void reduce_M_kernel(
    const float* __restrict__ Mpart, float* __restrict__ Mred) {
  const int idx = blockIdx.x * 256 + threadIdx.x;
  const int bh = idx >> 12, e = idx & 4095;
  float s = 0.f;
#pragma unroll
  for (int c = 0; c < 16; ++c) s += Mpart[((size_t)bh * 16 + c) * 4096 + e];
  Mred[idx] = s * 0.125f;
}

// ---------------------------------------------------------------------------
// Ct[b][j][k] = sum_i M[b,h(k)][k&63][i] * w_o[j][h(k)*64+i]
// ---------------------------------------------------------------------------
__global__ __launch_bounds__(256) void build_C_kernel(
    const float* __restrict__ Mred, const ushort_t* __restrict__ Wo,
    ushort_t* __restrict__ Ct) {
  const int blk = blockIdx.x;
  const int b = blk >> 8, h = (blk >> 4) & 15, jb = blk & 15;
  __shared__ float sM[64][65];
  __shared__ __align__(16) ushort_t sW[64][72];
  const int t = threadIdx.x;
  const float* Mp = Mred + (size_t)(b * 16 + h) * 4096;
#pragma unroll
  for (int i = 0; i < 16; ++i) {
    const int e = t + i * 256;
    sM[e >> 6][e & 63] = Mp[e];
  }
  const int j0 = jb * 64;
#pragma unroll
  for (int i = 0; i < 2; ++i) {
    const int ch = t + i * 256;
    const int row = ch >> 3, cc = ch & 7;
    *(short8*)&sW[row][cc * 8] =
        *(const short8*)&Wo[(size_t)(j0 + row) * ND + h * 64 + cc * 8];
  }
  __syncthreads();
  const int kk = (t & 15) * 4, jj = (t >> 4) * 4;
  float acc[4][4] = {};
  for (int i = 0; i < 64; ++i) {
    float mv[4], wv[4];
#pragma unroll
    for (int a2 = 0; a2 < 4; ++a2) mv[a2] = sM[kk + a2][i];
#pragma unroll
    for (int b2 = 0; b2 < 4; ++b2) wv[b2] = bf2f(sW[jj + b2][i]);
#pragma unroll
    for (int a2 = 0; a2 < 4; ++a2)
#pragma unroll
      for (int b2 = 0; b2 < 4; ++b2) acc[a2][b2] += mv[a2] * wv[b2];
  }
#pragma unroll
  for (int a2 = 0; a2 < 4; ++a2)
#pragma unroll
    for (int b2 = 0; b2 < 4; ++b2)
      Ct[((size_t)b * ND + j0 + jj + b2) * ND + h * 64 + kk + a2] =
          f2bf(acc[a2][b2]);
}

// ---------------------------------------------------------------------------
extern "C" void kernel_launch(void* const* d_in, const int* in_sizes, int n_in,
                              void* d_out, int out_size, void* d_ws,
                              size_t ws_size, hipStream_t stream) {
  (void)in_sizes; (void)n_in; (void)out_size; (void)ws_size;
  const float* q = (const float*)d_in[0];
  const float* k = (const float*)d_in[1];
  const float* v = (const float*)d_in[2];
  const float* wq = (const float*)d_in[3];
  const float* bq = (const float*)d_in[4];
  const float* wk = (const float*)d_in[5];
  const float* bk = (const float*)d_in[6];
  const float* wv = (const float*)d_in[7];
  const float* bv = (const float*)d_in[8];
  const float* wo = (const float*)d_in[9];
  const float* bo = (const float*)d_in[10];
  float* out = (float*)d_out;

  const size_t MB = 1048576;
  char* ws = (char*)d_ws;
  ushort_t* Xq = (ushort_t*)(ws + 0 * MB);
  ushort_t* Xk = (ushort_t*)(ws + 8 * MB);
  ushort_t* Xv = (ushort_t*)(ws + 16 * MB);
  ushort_t* Wq = (ushort_t*)(ws + 24 * MB);
  ushort_t* Wk = (ushort_t*)(ws + 26 * MB);
  ushort_t* Wv = (ushort_t*)(ws + 28 * MB);
  ushort_t* Wo = (ushort_t*)(ws + 30 * MB);
  ushort_t* Qb = (ushort_t*)(ws + 32 * MB);
  ushort_t* Kb = (ushort_t*)(ws + 40 * MB);
  ushort_t* Vb = (ushort_t*)(ws + 48 * MB);
  float* Mpart = (float*)(ws + 0 * MB);
  float* Mred = (float*)(ws + 8 * MB);
  ushort_t* Ct = (ushort_t*)(ws + 8 * MB + 524288);

  hipLaunchKernelGGL(convert_kernel, dim3(8192), dim3(256), 0, stream, q, k, v,
                     wq, wk, wv, wo, Xq, Xk, Xv, Wq, Wk, Wv, Wo);
  hipLaunchKernelGGL(proj_qkv_kernel, dim3(768), dim3(256), 0, stream, Xq, Xk,
                     Xv, Wq, Wk, Wv, bq, bk, bv, Qb, Kb, Vb);
  hipLaunchKernelGGL(kv_outer_kernel, dim3(512), dim3(256), 0, stream, Kb, Vb,
                     Mpart);
  hipLaunchKernelGGL(reduce_M_kernel, dim3(512), dim3(256), 0, stream, Mpart,
                     Mred);
  hipLaunchKernelGGL(build_C_kernel, dim3(512), dim3(256), 0, stream, Mred, Wo,
                     Ct);
  hipLaunchKernelGGL(out_gemm_kernel, dim3(512), dim3(256), 0, stream, Qb, Ct,
                     bo, out);
}